// Round 12
// baseline (1885.144 us; speedup 1.0000x reference)
//
#include <hip/hip_runtime.h>
#include <hip/hip_bf16.h>
#include <stdint.h>

// Problem constants (fixed by reference)
#define BATCH 16
#define NPTS  8192
#define NCH   6
#define NGRP  512   // NUM_GROUPS (FPS samples)
#define GSZ   32    // GROUP_SIZE (kNN)

#define FPS_T  1024            // threads per fps block (16 waves)
#define FPS_Q  4               // blocks (CUs) cooperating per batch
#define FPS_W  16
#define PPB    (NPTS / FPS_Q)  // 2048 points per block -> 2 per thread (1 v2f)

typedef float v2f __attribute__((ext_vector_type(2)));

// DPP ctrl encodings (gfx9+): row_shr:N = 0x110|N, row_bcast15/31 = 0x142/0x143
template <int CTRL>
__device__ __forceinline__ float dpp_max_f32(float v) {
  // bound_ctrl=1 -> invalid source lanes read 0; reduced values are squared
  // distances >= 0, so max-with-0 is identity-safe. (validated r7-r11)
  const int t =
      __builtin_amdgcn_update_dpp(0, __float_as_int(v), CTRL, 0xf, 0xf, true);
  return fmaxf(v, __int_as_float(t));
}

template <int CTRL>
__device__ __forceinline__ unsigned dpp_min_u32(unsigned v) {
  // bound_ctrl=0 + old=0xFFFFFFFF -> invalid lanes yield the min identity.
  const int t = __builtin_amdgcn_update_dpp((int)0xFFFFFFFF, (int)v, CTRL,
                                            0xf, 0xf, false);
  const unsigned tu = (unsigned)t;
  return v < tu ? v : tu;
}

// ---------------------------------------------------------------------------
// Kernel 1: farthest point sampling, 4 CUs per batch (64 blocks total).
// Each block owns a contiguous quarter of the batch's points (2 pts/thread).
// Per step: r7-verbatim per-point update + DPP/ballot block reduce, then the
// block's unique owner thread publishes {x,y,z,key} to a double-buffered,
// sequence-tagged global slot (relaxed xyz, RELEASE key, agent scope); wave 0
// of every block ACQUIRE-polls the 4 partner slots, combines (max val, tie
// min idx via (val<<32)|(8191-idx) max; partitions disjoint -> keys unique),
// and LDS-broadcasts the winner coords.
//
// Safety: double-buffered slots + publish(k+2) gated on poll(k+1) gated on
// partner publish(k+1) gated on partner poll(k) => a slot for step k is never
// overwritten before every partner has read it. Progress requires the 64
// blocks to be co-resident (64 blocks x 1024 thr on a dedicated 256-CU GPU;
// accepted risk, flagged). 0xAA ws poison can't alias a tag: 0xAAAAAAAA>>13 =
// 349525 > 511. Partner group {b, b+16, b+32, b+48} shares blockIdx%8 ->
// same-XCD L2 under the usual round-robin mapping (perf heuristic only).
//
// Numerics (bit-exact, r2/r4/r7-r11): d=(dx*dx+dy*dy)+dz*dz, contract off,
// elementwise min, fmaxf; argmax-first == value max then min index, resolved
// min-j -> min-lane (ballot ctz) -> min-wave (ballot ctz) -> min-block
// (combine tie-break). Per-point arithmetic independent of partitioning.
// ---------------------------------------------------------------------------
__global__ __launch_bounds__(FPS_T, 1) void fps_kernel(
    const float* __restrict__ points, float* __restrict__ centers,
    unsigned* __restrict__ ws) {
#pragma clang fp contract(off)
  const int b    = blockIdx.x & 15;   // batch
  const int q    = blockIdx.x >> 4;   // quarter within batch
  const int tid  = threadIdx.x;
  const int lane = tid & 63;
  const int wave = tid >> 6;
  const float* P = points + (size_t)b * NPTS * NCH;
  float* C = centers + (size_t)b * NGRP * 3;

  __shared__ unsigned long long wslot[2][FPS_W];
  __shared__ float bc[2][3];          // broadcast winner coords

  const int i0 = q * PPB + tid * 2;   // global (within batch) idx of md.x
  v2f px, py, pz, md;
  px.x = P[i0 * 6 + 0];       py.x = P[i0 * 6 + 1];       pz.x = P[i0 * 6 + 2];
  px.y = P[(i0 + 1) * 6 + 0]; py.y = P[(i0 + 1) * 6 + 1]; pz.y = P[(i0 + 1) * 6 + 2];
  md = (v2f){__builtin_inff(), __builtin_inff()};

  float lx = P[0], ly = P[1], lz = P[2];  // center 0 = point 0 (uniform)

  for (int k = 1; k < NGRP; ++k) {
    if (q == 0 && tid == 0) {  // store center k-1 (off critical path)
      C[(k - 1) * 3 + 0] = lx; C[(k - 1) * 3 + 1] = ly; C[(k - 1) * 3 + 2] = lz;
    }

    // ---- inner: one packed min-dist update (bit-exact ref order) ----
    const v2f vlx = {lx, lx}, vly = {ly, ly}, vlz = {lz, lz};
    const v2f dx = px - vlx;
    const v2f dy = py - vly;
    const v2f dz = pz - vlz;
    const v2f d  = (dx * dx + dy * dy) + dz * dz;
    md = __builtin_elementwise_min(md, d);
    const float bestv = fmaxf(md.x, md.y);
    unsigned idxbest = 0;
    idxbest = (md.y == bestv) ? (unsigned)(i0 + 1) : idxbest;
    idxbest = (md.x == bestv) ? (unsigned)i0       : idxbest;  // min idx last

    // ---- level-1: wave max via DPP, owner = first matching lane ----
    float wv = bestv;
    wv = dpp_max_f32<0x111>(wv); wv = dpp_max_f32<0x112>(wv);
    wv = dpp_max_f32<0x114>(wv); wv = dpp_max_f32<0x118>(wv);
    wv = dpp_max_f32<0x142>(wv); wv = dpp_max_f32<0x143>(wv);
    const float wvmax =
        __int_as_float(__builtin_amdgcn_readlane(__float_as_int(wv), 63));
    const int owner = (int)__builtin_ctzll(__ballot(bestv == wvmax));

    const int p = k & 1;
    if (lane == owner)
      wslot[p][wave] =
          ((unsigned long long)__float_as_uint(wvmax) << 32) | idxbest;
    __syncthreads();  // bar1

    // ---- level-2: 16 slots, DPP row max + ballot (min wave) ----
    const unsigned long long slot = wslot[p][lane & 15];
    const float sval = __uint_as_float((unsigned)(slot >> 32));
    float r = sval;
    r = dpp_max_f32<0x111>(r); r = dpp_max_f32<0x112>(r);
    r = dpp_max_f32<0x114>(r); r = dpp_max_f32<0x118>(r);
    const float gmax =
        __int_as_float(__builtin_amdgcn_readlane(__float_as_int(r), 15));
    const int sstar =
        (int)__builtin_ctzll(__ballot(sval == gmax) & 0xFFFFull);

    // ---- publish block winner to global slot (unique thread) ----
    if (wave == sstar && lane == owner) {
      float fx = 0.f, fy = 0.f, fz = 0.f;  // coords of lowest matching idx
      if (md.y == bestv) { fx = px.y; fy = py.y; fz = pz.y; }
      if (md.x == bestv) { fx = px.x; fy = py.x; fz = pz.x; }
      unsigned* g = ws + (((unsigned)(b * FPS_Q + q) * 2u + (unsigned)p) * 8u);
      __hip_atomic_store(g + 2, __float_as_uint(fx), __ATOMIC_RELAXED,
                         __HIP_MEMORY_SCOPE_AGENT);
      __hip_atomic_store(g + 3, __float_as_uint(fy), __ATOMIC_RELAXED,
                         __HIP_MEMORY_SCOPE_AGENT);
      __hip_atomic_store(g + 4, __float_as_uint(fz), __ATOMIC_RELAXED,
                         __HIP_MEMORY_SCOPE_AGENT);
      const unsigned long long key =
          ((unsigned long long)__float_as_uint(wvmax) << 32) |
          ((unsigned)k << 13) | idxbest;  // idx < 8192 = 13 bits
      __hip_atomic_store((unsigned long long*)g, key, __ATOMIC_RELEASE,
                         __HIP_MEMORY_SCOPE_AGENT);
    }

    // ---- wave 0: poll 4 partner slots, combine, broadcast ----
    if (wave == 0) {
      unsigned long long kk = 0ull, kk0;
      float wxr = 0.f, wyr = 0.f, wzr = 0.f;
      if (lane < FPS_Q) {
        unsigned* g =
            ws + (((unsigned)(b * FPS_Q + lane) * 2u + (unsigned)p) * 8u);
        unsigned long long key;
        for (;;) {
          key = __hip_atomic_load((unsigned long long*)g, __ATOMIC_ACQUIRE,
                                  __HIP_MEMORY_SCOPE_AGENT);
          if ((unsigned)((key & 0xFFFFFFFFull) >> 13) == (unsigned)k) break;
        }
        wxr = __uint_as_float(__hip_atomic_load(g + 2, __ATOMIC_RELAXED,
                                                __HIP_MEMORY_SCOPE_AGENT));
        wyr = __uint_as_float(__hip_atomic_load(g + 3, __ATOMIC_RELAXED,
                                                __HIP_MEMORY_SCOPE_AGENT));
        wzr = __uint_as_float(__hip_atomic_load(g + 4, __ATOMIC_RELAXED,
                                                __HIP_MEMORY_SCOPE_AGENT));
        const unsigned idx = (unsigned)key & 0x1FFFu;
        const unsigned val = (unsigned)(key >> 32);
        kk = ((unsigned long long)val << 32) |
             (unsigned long long)(8191u - idx);  // max => val max, tie min idx
      }
      kk0 = kk;
      { const unsigned long long o = __shfl_xor(kk, 1); kk = kk > o ? kk : o; }
      { const unsigned long long o = __shfl_xor(kk, 2); kk = kk > o ? kk : o; }
      const int wl =
          (int)__builtin_ctzll(__ballot(lane < FPS_Q && kk0 == kk));
      const float bx =
          __uint_as_float(__builtin_amdgcn_readlane(__float_as_int(wxr), wl));
      const float by =
          __uint_as_float(__builtin_amdgcn_readlane(__float_as_int(wyr), wl));
      const float bz =
          __uint_as_float(__builtin_amdgcn_readlane(__float_as_int(wzr), wl));
      if (lane == 0) { bc[p][0] = bx; bc[p][1] = by; bc[p][2] = bz; }
    }
    __syncthreads();  // bar2
    lx = bc[p][0]; ly = bc[p][1]; lz = bc[p][2];
  }
  if (q == 0 && tid == 0) {  // final center
    C[(NGRP - 1) * 3 + 0] = lx;
    C[(NGRP - 1) * 3 + 1] = ly;
    C[(NGRP - 1) * 3 + 2] = lz;
  }
}

// ---------------------------------------------------------------------------
// Kernel 2: 32-NN per (batch, group) — ROUND-10/11 VERBATIM (best measured:
// ~268-285 us). VALU-only DPP pair per round (u32 val-min then idx-min ==
// lexicographic u64 key min, identical tie-breaks).
// ---------------------------------------------------------------------------
__global__ __launch_bounds__(256) void knn_kernel(
    const float* __restrict__ points, const float* __restrict__ centers,
    float* __restrict__ grouped) {
#pragma clang fp contract(off)
  const int g    = blockIdx.x;
  const int b    = blockIdx.y;
  const int tid  = threadIdx.x;
  const int lane = tid & 63;
  const int wave = tid >> 6;
  const float* P   = points + (size_t)b * NPTS * NCH;
  const float* cen = centers + ((size_t)b * NGRP + g) * 3;
  const float cx = cen[0], cy = cen[1], cz = cen[2];
  const float cc = (cx * cx + cy * cy) + cz * cz;

  unsigned long long keys[32];
  for (int j = 0; j < 32; ++j) {
    const int i = j * 256 + tid;
    const float x = P[i * 6 + 0];
    const float y = P[i * 6 + 1];
    const float z = P[i * 6 + 2];
    const float xx  = (x * x + y * y) + z * z;
    const float dot = fmaf(cz, z, fmaf(cy, y, cx * x));  // einsum fma chain
    const float d2  = (cc - 2.0f * dot) + xx;
    unsigned u = __float_as_uint(d2);
    u = (u & 0x80000000u) ? ~u : (u | 0x80000000u);  // sortable map
    keys[j] = ((unsigned long long)u << 32) | (unsigned long long)(unsigned)i;
  }
  unsigned long long lmin = keys[0];
  for (int j = 1; j < 32; ++j) lmin = lmin < keys[j] ? lmin : keys[j];

  __shared__ unsigned long long wred[2][4];
  __shared__ int knn_sh[GSZ];

  for (int j = 0; j < GSZ; ++j) {
    const unsigned vcur = (unsigned)(lmin >> 32);
    const unsigned icur = (unsigned)(lmin & 0xFFFFFFFFull);
    unsigned vm = vcur;
    vm = dpp_min_u32<0x111>(vm); vm = dpp_min_u32<0x112>(vm);
    vm = dpp_min_u32<0x114>(vm); vm = dpp_min_u32<0x118>(vm);
    vm = dpp_min_u32<0x142>(vm); vm = dpp_min_u32<0x143>(vm);
    const unsigned vmin = (unsigned)__builtin_amdgcn_readlane((int)vm, 63);
    unsigned ic = (vcur == vmin) ? icur : 0xFFFFFFFFu;
    ic = dpp_min_u32<0x111>(ic); ic = dpp_min_u32<0x112>(ic);
    ic = dpp_min_u32<0x114>(ic); ic = dpp_min_u32<0x118>(ic);
    ic = dpp_min_u32<0x142>(ic); ic = dpp_min_u32<0x143>(ic);
    const unsigned imin = (unsigned)__builtin_amdgcn_readlane((int)ic, 63);

    if (lane == 0)
      wred[j & 1][wave] =
          ((unsigned long long)vmin << 32) | (unsigned long long)imin;
    __syncthreads();
    unsigned long long w = wred[j & 1][0];
    for (int q2 = 1; q2 < 4; ++q2) {
      const unsigned long long o = wred[j & 1][q2];
      w = w < o ? w : o;
    }
    const int widx = (int)(unsigned)(w & 0xFFFFFFFFull);
    if (tid == (widx & 255)) {  // owner removes winner, rebuilds local min
      for (int s = 0; s < 32; ++s)
        if ((unsigned)(keys[s] & 0xFFFFFFFFull) == (unsigned)widx)
          keys[s] = ~0ull;
      lmin = keys[0];
      for (int s = 1; s < 32; ++s) lmin = lmin < keys[s] ? lmin : keys[s];
    }
    if (tid == 0) knn_sh[j] = widx;
  }
  __syncthreads();

  // gather + center-relative xyz; 192 output floats per group
  float* outg = grouped + ((size_t)b * NGRP + g) * GSZ * NCH;
  for (int t = tid; t < GSZ * NCH; t += 256) {
    const int n = t / 6, c = t % 6;
    const int idx = knn_sh[n];
    float v = P[idx * 6 + c];
    if (c < 3) v = v - cen[c];  // exact ref subtract
    outg[t] = v;
  }
}

extern "C" void kernel_launch(void* const* d_in, const int* in_sizes, int n_in,
                              void* d_out, int out_size, void* d_ws, size_t ws_size,
                              hipStream_t stream) {
  const float* points = (const float*)d_in[0];
  float* out = (float*)d_out;
  float* grouped = out;                                        // [16,512,32,6]
  float* centers = out + (size_t)BATCH * NGRP * GSZ * NCH;     // [16,512,3]
  unsigned* ws = (unsigned*)d_ws;  // 4 KB of seq-tagged slots (0xAA-safe)

  fps_kernel<<<BATCH * FPS_Q, FPS_T, 0, stream>>>(points, centers, ws);
  knn_kernel<<<dim3(NGRP, BATCH), 256, 0, stream>>>(points, centers, grouped);
}

// Round 13
// 824.237 us; speedup vs baseline: 2.2871x; 2.2871x over previous
//
#include <hip/hip_runtime.h>
#include <hip/hip_bf16.h>
#include <stdint.h>

// Problem constants (fixed by reference)
#define BATCH 16
#define NPTS  8192
#define NCH   6
#define NGRP  512   // NUM_GROUPS (FPS samples)
#define GSZ   32    // GROUP_SIZE (kNN)

#define FPS_T   1024              // 16 waves, 4/SIMD
#define FPS_PPT 8                 // contiguous: idx = tid*8 + j
#define FPS_W   16

typedef float v2f __attribute__((ext_vector_type(2)));

// DPP ctrl encodings (gfx9+): row_shr:N = 0x110|N, row_bcast15/31 = 0x142/0x143
template <int CTRL>
__device__ __forceinline__ float dpp_max_f32(float v) {
  // bound_ctrl=1 -> invalid source lanes read 0; reduced values are squared
  // distances >= 0, so max-with-0 is identity-safe. (validated r7-r12)
  const int t =
      __builtin_amdgcn_update_dpp(0, __float_as_int(v), CTRL, 0xf, 0xf, true);
  return fmaxf(v, __int_as_float(t));
}

template <int CTRL>
__device__ __forceinline__ unsigned dpp_min_u32(unsigned v) {
  // bound_ctrl=0 + old=0xFFFFFFFF -> invalid lanes yield the min identity.
  const int t = __builtin_amdgcn_update_dpp((int)0xFFFFFFFF, (int)v, CTRL,
                                            0xf, 0xf, false);
  const unsigned tu = (unsigned)t;
  return v < tu ? v : tu;
}

// ---------------------------------------------------------------------------
// Kernel 1: farthest point sampling — r7 structure (best measured) with the
// per-step __syncthreads replaced by an LDS sequence-tag handshake.
//
// WHY: __syncthreads emits `s_waitcnt vmcnt(0) lgkmcnt(0); s_barrier`, which
// drains wave 0's per-step GLOBAL C-store (~400-900 cyc HBM store ack) into
// EVERY step's critical path. The tag handshake waits only on the 16 LDS
// slot tags; the C-store becomes fire-and-forget.
//
// Handshake safety: each wave writes its slot data (relaxed, workgroup) then
// tag=k (RELEASE); polls all 16 tags (ACQUIRE) until ballot-full. Tags
// strictly increase -> no ABA. Slots double-buffered by k&1 -> a slot is
// only rewritten at k+2, a full inner-loop after all consumers read step k.
// Every wave writes before polling -> no circular wait; all 16 waves of the
// block are co-resident on one CU by construction.
//
// Numerics (bit-exact, r2/r4/r7/r11): d = (dx*dx+dy*dy)+dz*dz, contract off
// (pk ops per-element IEEE), fminf running min. argmax-first == value max,
// then min index == first matching lane (contiguous mapping idx = tid*8+j),
// then min j (descending overwrite); cross-wave ties -> min wave (== min
// index) via ballot ctz. Selection arithmetic is UNCHANGED from r7/r11.
// ---------------------------------------------------------------------------
__global__ __launch_bounds__(FPS_T, 1) void fps_kernel(
    const float* __restrict__ points, float* __restrict__ centers) {
#pragma clang fp contract(off)
  const int b    = blockIdx.x;
  const int tid  = threadIdx.x;
  const int lane = tid & 63;
  const int wave = tid >> 6;
  const float* P = points + (size_t)b * NPTS * NCH;
  float* C = centers + (size_t)b * NGRP * 3;

  __shared__ float cache[NPTS * 3];                    // xyz cache, 96 KiB
  __shared__ unsigned long long wdata[2][FPS_W];       // slot data (val,idx)
  __shared__ unsigned wtag[2][FPS_W];                  // slot sequence tags

  v2f px[4], py[4], pz[4], md[4];
  {
    float* fx = (float*)px; float* fy = (float*)py; float* fz = (float*)pz;
#pragma unroll
    for (int j = 0; j < FPS_PPT; ++j) {
      const int i = tid * FPS_PPT + j;   // contiguous mapping
      const float x = P[i * 6 + 0];
      const float y = P[i * 6 + 1];
      const float z = P[i * 6 + 2];
      fx[j] = x; fy[j] = y; fz[j] = z;
      cache[i * 3 + 0] = x;
      cache[i * 3 + 1] = y;
      cache[i * 3 + 2] = z;
    }
#pragma unroll
    for (int j = 0; j < 4; ++j) md[j] = (v2f){__builtin_inff(), __builtin_inff()};
  }
  if (tid < 32) wtag[tid >> 4][tid & 15] = 0;  // tags start below any k
  __syncthreads();  // cache + tag init ready (the ONLY barrier)

  // current center = point 0
  float lx = cache[0], ly = cache[1], lz = cache[2];

  for (int k = 1; k < NGRP; ++k) {
    if (tid == 0) {  // fire-and-forget global store (nothing waits on it)
      C[(k - 1) * 3 + 0] = lx; C[(k - 1) * 3 + 1] = ly; C[(k - 1) * 3 + 2] = lz;
    }

    // ---- inner: packed min-dist update + per-thread max ----
    const v2f vlx = {lx, lx}, vly = {ly, ly}, vlz = {lz, lz};
    v2f b2 = {-__builtin_inff(), -__builtin_inff()};
#pragma unroll
    for (int j = 0; j < 4; ++j) {
      const v2f dx = px[j] - vlx;
      const v2f dy = py[j] - vly;
      const v2f dz = pz[j] - vlz;
      const v2f d  = (dx * dx + dy * dy) + dz * dz;  // ref op order, no fma
      md[j] = __builtin_elementwise_min(md[j], d);
      b2 = __builtin_elementwise_max(b2, md[j]);
    }
    const float bestv = fmaxf(b2.x, b2.y);

    // first (min) index attaining bestv: descending scan ends at min j
    unsigned idxbest = 0;
#pragma unroll
    for (int j = 3; j >= 0; --j) {
      idxbest = (md[j].y == bestv) ? (unsigned)(tid * 8 + 2 * j + 1) : idxbest;
      idxbest = (md[j].x == bestv) ? (unsigned)(tid * 8 + 2 * j)     : idxbest;
    }

    // ---- level-1: wave max via DPP (VALU only) ----
    float wv = bestv;
    wv = dpp_max_f32<0x111>(wv); wv = dpp_max_f32<0x112>(wv);
    wv = dpp_max_f32<0x114>(wv); wv = dpp_max_f32<0x118>(wv);
    wv = dpp_max_f32<0x142>(wv); wv = dpp_max_f32<0x143>(wv);
    const float wvmax =
        __int_as_float(__builtin_amdgcn_readlane(__float_as_int(wv), 63));
    const int owner = (int)__builtin_ctzll(__ballot(bestv == wvmax));

    const int p = k & 1;
    if (lane == owner) {
      __hip_atomic_store(&wdata[p][wave],
                         ((unsigned long long)__float_as_uint(wvmax) << 32) |
                             idxbest,
                         __ATOMIC_RELAXED, __HIP_MEMORY_SCOPE_WORKGROUP);
      __hip_atomic_store(&wtag[p][wave], (unsigned)k, __ATOMIC_RELEASE,
                         __HIP_MEMORY_SCOPE_WORKGROUP);
    }

    // ---- tag poll replaces __syncthreads (no vmcnt drain) ----
    unsigned tg;
    do {
      tg = __hip_atomic_load(&wtag[p][lane & 15], __ATOMIC_ACQUIRE,
                             __HIP_MEMORY_SCOPE_WORKGROUP);
    } while (__ballot(tg == (unsigned)k) != ~0ull);

    // ---- level-2: 16 slots, row-replicated; DPP row max + ballot ----
    const unsigned long long slot =
        __hip_atomic_load(&wdata[p][lane & 15], __ATOMIC_RELAXED,
                          __HIP_MEMORY_SCOPE_WORKGROUP);
    const unsigned sidx = (unsigned)(slot & 0xFFFFFFFFull);
    const float    sval = __uint_as_float((unsigned)(slot >> 32));
    // speculative candidate coords (overlap the DPP reduce below)
    const float ccx = cache[sidx * 3 + 0];
    const float ccy = cache[sidx * 3 + 1];
    const float ccz = cache[sidx * 3 + 2];

    float r = sval;
    r = dpp_max_f32<0x111>(r); r = dpp_max_f32<0x112>(r);
    r = dpp_max_f32<0x114>(r); r = dpp_max_f32<0x118>(r);
    const float gmax =
        __int_as_float(__builtin_amdgcn_readlane(__float_as_int(r), 15));
    const int sstar =
        (int)__builtin_ctzll(__ballot(sval == gmax) & 0xFFFFull);  // min wave
    lx = __int_as_float(__builtin_amdgcn_readlane(__float_as_int(ccx), sstar));
    ly = __int_as_float(__builtin_amdgcn_readlane(__float_as_int(ccy), sstar));
    lz = __int_as_float(__builtin_amdgcn_readlane(__float_as_int(ccz), sstar));
  }
  if (tid == 0) {  // final center
    C[(NGRP - 1) * 3 + 0] = lx;
    C[(NGRP - 1) * 3 + 1] = ly;
    C[(NGRP - 1) * 3 + 2] = lz;
  }
}

// ---------------------------------------------------------------------------
// Kernel 2: 32-NN per (batch, group) — ROUND-10/11 VERBATIM (best measured:
// ~268-285 us). VALU-only DPP pair per round (u32 val-min then idx-min ==
// lexicographic u64 key min, identical tie-breaks).
// ---------------------------------------------------------------------------
__global__ __launch_bounds__(256) void knn_kernel(
    const float* __restrict__ points, const float* __restrict__ centers,
    float* __restrict__ grouped) {
#pragma clang fp contract(off)
  const int g    = blockIdx.x;
  const int b    = blockIdx.y;
  const int tid  = threadIdx.x;
  const int lane = tid & 63;
  const int wave = tid >> 6;
  const float* P   = points + (size_t)b * NPTS * NCH;
  const float* cen = centers + ((size_t)b * NGRP + g) * 3;
  const float cx = cen[0], cy = cen[1], cz = cen[2];
  const float cc = (cx * cx + cy * cy) + cz * cz;

  unsigned long long keys[32];
  for (int j = 0; j < 32; ++j) {
    const int i = j * 256 + tid;
    const float x = P[i * 6 + 0];
    const float y = P[i * 6 + 1];
    const float z = P[i * 6 + 2];
    const float xx  = (x * x + y * y) + z * z;
    const float dot = fmaf(cz, z, fmaf(cy, y, cx * x));  // einsum fma chain
    const float d2  = (cc - 2.0f * dot) + xx;
    unsigned u = __float_as_uint(d2);
    u = (u & 0x80000000u) ? ~u : (u | 0x80000000u);  // sortable map
    keys[j] = ((unsigned long long)u << 32) | (unsigned long long)(unsigned)i;
  }
  unsigned long long lmin = keys[0];
  for (int j = 1; j < 32; ++j) lmin = lmin < keys[j] ? lmin : keys[j];

  __shared__ unsigned long long wred[2][4];
  __shared__ int knn_sh[GSZ];

  for (int j = 0; j < GSZ; ++j) {
    const unsigned vcur = (unsigned)(lmin >> 32);
    const unsigned icur = (unsigned)(lmin & 0xFFFFFFFFull);
    unsigned vm = vcur;
    vm = dpp_min_u32<0x111>(vm); vm = dpp_min_u32<0x112>(vm);
    vm = dpp_min_u32<0x114>(vm); vm = dpp_min_u32<0x118>(vm);
    vm = dpp_min_u32<0x142>(vm); vm = dpp_min_u32<0x143>(vm);
    const unsigned vmin = (unsigned)__builtin_amdgcn_readlane((int)vm, 63);
    unsigned ic = (vcur == vmin) ? icur : 0xFFFFFFFFu;
    ic = dpp_min_u32<0x111>(ic); ic = dpp_min_u32<0x112>(ic);
    ic = dpp_min_u32<0x114>(ic); ic = dpp_min_u32<0x118>(ic);
    ic = dpp_min_u32<0x142>(ic); ic = dpp_min_u32<0x143>(ic);
    const unsigned imin = (unsigned)__builtin_amdgcn_readlane((int)ic, 63);

    if (lane == 0)
      wred[j & 1][wave] =
          ((unsigned long long)vmin << 32) | (unsigned long long)imin;
    __syncthreads();
    unsigned long long w = wred[j & 1][0];
    for (int q2 = 1; q2 < 4; ++q2) {
      const unsigned long long o = wred[j & 1][q2];
      w = w < o ? w : o;
    }
    const int widx = (int)(unsigned)(w & 0xFFFFFFFFull);
    if (tid == (widx & 255)) {  // owner removes winner, rebuilds local min
      for (int s = 0; s < 32; ++s)
        if ((unsigned)(keys[s] & 0xFFFFFFFFull) == (unsigned)widx)
          keys[s] = ~0ull;
      lmin = keys[0];
      for (int s = 1; s < 32; ++s) lmin = lmin < keys[s] ? lmin : keys[s];
    }
    if (tid == 0) knn_sh[j] = widx;
  }
  __syncthreads();

  // gather + center-relative xyz; 192 output floats per group
  float* outg = grouped + ((size_t)b * NGRP + g) * GSZ * NCH;
  for (int t = tid; t < GSZ * NCH; t += 256) {
    const int n = t / 6, c = t % 6;
    const int idx = knn_sh[n];
    float v = P[idx * 6 + c];
    if (c < 3) v = v - cen[c];  // exact ref subtract
    outg[t] = v;
  }
}

extern "C" void kernel_launch(void* const* d_in, const int* in_sizes, int n_in,
                              void* d_out, int out_size, void* d_ws, size_t ws_size,
                              hipStream_t stream) {
  const float* points = (const float*)d_in[0];
  float* out = (float*)d_out;
  float* grouped = out;                                        // [16,512,32,6]
  float* centers = out + (size_t)BATCH * NGRP * GSZ * NCH;     // [16,512,3]

  fps_kernel<<<BATCH, FPS_T, 0, stream>>>(points, centers);
  knn_kernel<<<dim3(NGRP, BATCH), 256, 0, stream>>>(points, centers, grouped);
}

// Round 14
// 741.745 us; speedup vs baseline: 2.5415x; 1.1112x over previous
//
#include <hip/hip_runtime.h>
#include <hip/hip_bf16.h>
#include <stdint.h>

// Problem constants (fixed by reference)
#define BATCH 16
#define NPTS  8192
#define NCH   6
#define NGRP  512   // NUM_GROUPS (FPS samples)
#define GSZ   32    // GROUP_SIZE (kNN)

#define FPS_T   1024              // 16 waves, 4/SIMD
#define FPS_PPT 8                 // contiguous: idx = tid*8 + j
#define FPS_W   16

typedef float v2f __attribute__((ext_vector_type(2)));

// DPP ctrl encodings (gfx9+): row_shr:N = 0x110|N, row_bcast15/31 = 0x142/0x143
template <int CTRL>
__device__ __forceinline__ float dpp_max_f32(float v) {
  // bound_ctrl=1 -> invalid source lanes read 0; reduced values are squared
  // distances >= 0, so max-with-0 is identity-safe. (validated r7-r13)
  const int t =
      __builtin_amdgcn_update_dpp(0, __float_as_int(v), CTRL, 0xf, 0xf, true);
  return fmaxf(v, __int_as_float(t));
}

template <int CTRL>
__device__ __forceinline__ unsigned dpp_min_u32(unsigned v) {
  // bound_ctrl=0 + old=0xFFFFFFFF -> invalid lanes yield the min identity.
  // (validated r10/r11)
  const int t = __builtin_amdgcn_update_dpp((int)0xFFFFFFFF, (int)v, CTRL,
                                            0xf, 0xf, false);
  const unsigned tu = (unsigned)t;
  return v < tu ? v : tu;
}

// ---------------------------------------------------------------------------
// Kernel 1: farthest point sampling — ROUND-7/11 VERBATIM (measured best
// 516-535 us across r7/r11/r13; plateau accepted after 6 variants).
// One barrier/step, DPP level-1 reduce, ballot index resolution under
// contiguous mapping (idx = tid*8+j), u64 slots, speculative coord gathers
// from a 96 KiB LDS cache overlapping the level-2 DPP chain, readlane finish.
//
// Numerics (bit-exact, r2/r4/r7/r11): d = (dx*dx+dy*dy)+dz*dz, contract off,
// fminf running min. argmax-first == value max, then min index == first
// matching lane, then min j (descending overwrite); cross-wave ties -> min
// wave via ballot ctz.
// ---------------------------------------------------------------------------
__global__ __launch_bounds__(FPS_T, 1) void fps_kernel(
    const float* __restrict__ points, float* __restrict__ centers) {
#pragma clang fp contract(off)
  const int b    = blockIdx.x;
  const int tid  = threadIdx.x;
  const int lane = tid & 63;
  const int wave = tid >> 6;
  const float* P = points + (size_t)b * NPTS * NCH;
  float* C = centers + (size_t)b * NGRP * 3;

  __shared__ float cache[NPTS * 3];                    // xyz cache, 96 KiB
  __shared__ unsigned long long wslot[2][FPS_W];       // ping-pong slots

  v2f px[4], py[4], pz[4], md[4];
  {
    float* fx = (float*)px; float* fy = (float*)py; float* fz = (float*)pz;
#pragma unroll
    for (int j = 0; j < FPS_PPT; ++j) {
      const int i = tid * FPS_PPT + j;   // contiguous mapping
      const float x = P[i * 6 + 0];
      const float y = P[i * 6 + 1];
      const float z = P[i * 6 + 2];
      fx[j] = x; fy[j] = y; fz[j] = z;
      cache[i * 3 + 0] = x;
      cache[i * 3 + 1] = y;
      cache[i * 3 + 2] = z;
    }
#pragma unroll
    for (int j = 0; j < 4; ++j) md[j] = (v2f){__builtin_inff(), __builtin_inff()};
  }
  __syncthreads();  // cache ready

  // current center = point 0
  float lx = cache[0], ly = cache[1], lz = cache[2];

  for (int k = 1; k < NGRP; ++k) {
    if (tid == 0) {  // store center k-1 (uniform regs, off critical path)
      C[(k - 1) * 3 + 0] = lx; C[(k - 1) * 3 + 1] = ly; C[(k - 1) * 3 + 2] = lz;
    }

    // ---- inner: packed min-dist update + per-thread max ----
    const v2f vlx = {lx, lx}, vly = {ly, ly}, vlz = {lz, lz};
    v2f b2 = {-__builtin_inff(), -__builtin_inff()};
#pragma unroll
    for (int j = 0; j < 4; ++j) {
      const v2f dx = px[j] - vlx;
      const v2f dy = py[j] - vly;
      const v2f dz = pz[j] - vlz;
      const v2f d  = (dx * dx + dy * dy) + dz * dz;  // ref op order, no fma
      md[j] = __builtin_elementwise_min(md[j], d);
      b2 = __builtin_elementwise_max(b2, md[j]);
    }
    const float bestv = fmaxf(b2.x, b2.y);

    // first (min) index attaining bestv: descending scan ends at min j
    unsigned idxbest = 0;
#pragma unroll
    for (int j = 3; j >= 0; --j) {
      idxbest = (md[j].y == bestv) ? (unsigned)(tid * 8 + 2 * j + 1) : idxbest;
      idxbest = (md[j].x == bestv) ? (unsigned)(tid * 8 + 2 * j)     : idxbest;
    }

    // ---- level-1: wave max via DPP (VALU only) ----
    float wv = bestv;
    wv = dpp_max_f32<0x111>(wv); wv = dpp_max_f32<0x112>(wv);
    wv = dpp_max_f32<0x114>(wv); wv = dpp_max_f32<0x118>(wv);
    wv = dpp_max_f32<0x142>(wv); wv = dpp_max_f32<0x143>(wv);
    const float wvmax =
        __int_as_float(__builtin_amdgcn_readlane(__float_as_int(wv), 63));

    // owner = first lane attaining wave max (== min index owner)
    const unsigned long long m1 = __ballot(bestv == wvmax);
    const int owner = (int)__builtin_ctzll(m1);
    if (lane == owner)
      wslot[k & 1][wave] =
          ((unsigned long long)__float_as_uint(wvmax) << 32) | idxbest;
    __syncthreads();  // the only barrier per step

    // ---- level-2: 16 slots, row-replicated; DPP row max + ballot ----
    const unsigned long long slot = wslot[k & 1][lane & 15];
    const unsigned sidx = (unsigned)(slot & 0xFFFFFFFFull);
    const float    sval = __uint_as_float((unsigned)(slot >> 32));
    // speculative candidate coords (overlaps the DPP reduce below)
    const float ccx = cache[sidx * 3 + 0];
    const float ccy = cache[sidx * 3 + 1];
    const float ccz = cache[sidx * 3 + 2];

    float r = sval;
    r = dpp_max_f32<0x111>(r); r = dpp_max_f32<0x112>(r);
    r = dpp_max_f32<0x114>(r); r = dpp_max_f32<0x118>(r);
    const float gmax =
        __int_as_float(__builtin_amdgcn_readlane(__float_as_int(r), 15));
    const int sstar =
        (int)__builtin_ctzll(__ballot(sval == gmax) & 0xFFFFull);  // min wave
    lx = __int_as_float(__builtin_amdgcn_readlane(__float_as_int(ccx), sstar));
    ly = __int_as_float(__builtin_amdgcn_readlane(__float_as_int(ccy), sstar));
    lz = __int_as_float(__builtin_amdgcn_readlane(__float_as_int(ccz), sstar));
  }
  if (tid == 0) {  // final center
    C[(NGRP - 1) * 3 + 0] = lx;
    C[(NGRP - 1) * 3 + 1] = ly;
    C[(NGRP - 1) * 3 + 2] = lz;
  }
}

// ---------------------------------------------------------------------------
// Kernel 2: 32-NN per (batch, group) — ROUND-14 RESTRUCTURE.
// Phase 1 (barrier-free): each wave extracts the top-32 of ITS 2048 keys via
// 32 DPP val/idx-min rounds (r10-validated reduce; owner = imin&63 directly,
// partitions are wave-aligned). Owner removal uses 4 group-mins (rescan 8 +
// recombine 4 instead of rescan 32 + rebuild 31). Union of per-wave top-32s
// contains the block top-32.
// Phase 2 (one barrier): wave 0 bitonic-sorts the 128 candidate u64 keys
// (64 lanes x 2 slots, 28 compare-exchange stages); ascending u64 order ==
// (d2, idx) lexicographic == exact lax.top_k order (keys unique since idx is
// embedded). First 32 = block result, sorted.
//
// Numerics (bit-exact, r2-validated): xx left-to-right, dot = fmaf chain
// (einsum), d2 = (cc-2*dot)+xx, sortable-u32 map, u64 keys, ascending-index
// tie-break. Key VALUES identical to r11; only the selection SCHEDULE changed
// (same total order -> same result).
// ---------------------------------------------------------------------------
__global__ __launch_bounds__(256) void knn_kernel(
    const float* __restrict__ points, const float* __restrict__ centers,
    float* __restrict__ grouped) {
#pragma clang fp contract(off)
  const int g    = blockIdx.x;
  const int b    = blockIdx.y;
  const int tid  = threadIdx.x;
  const int lane = tid & 63;
  const int wave = tid >> 6;
  const float* P   = points + (size_t)b * NPTS * NCH;
  const float* cen = centers + ((size_t)b * NGRP + g) * 3;
  const float cx = cen[0], cy = cen[1], cz = cen[2];
  const float cc = (cx * cx + cy * cy) + cz * cz;

  unsigned long long keys[32];
#pragma unroll
  for (int j = 0; j < 32; ++j) {
    const int i = j * 256 + tid;
    const float2 xy = *reinterpret_cast<const float2*>(P + (size_t)i * 6);
    const float x = xy.x, y = xy.y;
    const float z = P[i * 6 + 2];
    const float xx  = (x * x + y * y) + z * z;
    const float dot = fmaf(cz, z, fmaf(cy, y, cx * x));  // einsum fma chain
    const float d2  = (cc - 2.0f * dot) + xx;
    unsigned u = __float_as_uint(d2);
    u = (u & 0x80000000u) ? ~u : (u | 0x80000000u);  // sortable map
    keys[j] = ((unsigned long long)u << 32) | (unsigned long long)(unsigned)i;
  }

  // 4 group mins (8 keys each) + overall min
  unsigned long long gm[4];
#pragma unroll
  for (int g2 = 0; g2 < 4; ++g2) {
    unsigned long long m = keys[g2 * 8];
#pragma unroll
    for (int t = 1; t < 8; ++t) {
      const unsigned long long o = keys[g2 * 8 + t];
      m = m < o ? m : o;
    }
    gm[g2] = m;
  }
  unsigned long long lmin;
  {
    const unsigned long long a2 = gm[0] < gm[1] ? gm[0] : gm[1];
    const unsigned long long b3 = gm[2] < gm[3] ? gm[2] : gm[3];
    lmin = a2 < b3 ? a2 : b3;
  }

  __shared__ unsigned long long wtop[4][GSZ];  // per-wave sorted top-32
  __shared__ int knn_sh[GSZ];

  // ---- phase 1: per-wave top-32, NO barriers ----
  for (int r2 = 0; r2 < GSZ; ++r2) {
    const unsigned vcur = (unsigned)(lmin >> 32);
    const unsigned icur = (unsigned)(lmin & 0xFFFFFFFFull);
    unsigned vm = vcur;
    vm = dpp_min_u32<0x111>(vm); vm = dpp_min_u32<0x112>(vm);
    vm = dpp_min_u32<0x114>(vm); vm = dpp_min_u32<0x118>(vm);
    vm = dpp_min_u32<0x142>(vm); vm = dpp_min_u32<0x143>(vm);
    const unsigned vmin = (unsigned)__builtin_amdgcn_readlane((int)vm, 63);
    unsigned ic = (vcur == vmin) ? icur : 0xFFFFFFFFu;
    ic = dpp_min_u32<0x111>(ic); ic = dpp_min_u32<0x112>(ic);
    ic = dpp_min_u32<0x114>(ic); ic = dpp_min_u32<0x118>(ic);
    ic = dpp_min_u32<0x142>(ic); ic = dpp_min_u32<0x143>(ic);
    const unsigned imin = (unsigned)__builtin_amdgcn_readlane((int)ic, 63);
    const unsigned long long wk =
        ((unsigned long long)vmin << 32) | (unsigned long long)imin;

    // owner lane removes the winner (i = j*256+tid -> lane = imin & 63)
    if (lane == (int)(imin & 63u)) {
#pragma unroll
      for (int g2 = 0; g2 < 4; ++g2) {
        if (gm[g2] == wk) {  // exactly one group matches; execz skips others
          unsigned long long m = ~0ull;
#pragma unroll
          for (int t = 0; t < 8; ++t) {
            const int s = g2 * 8 + t;
            if (keys[s] == wk) keys[s] = ~0ull;
            const unsigned long long o = keys[s];
            m = m < o ? m : o;
          }
          gm[g2] = m;
        }
      }
      const unsigned long long a2 = gm[0] < gm[1] ? gm[0] : gm[1];
      const unsigned long long b3 = gm[2] < gm[3] ? gm[2] : gm[3];
      lmin = a2 < b3 ? a2 : b3;
    }
    if (lane == 0) wtop[wave][r2] = wk;
  }
  __syncthreads();  // wtop ready

  // ---- phase 2: wave 0 bitonic-sorts the 128 candidates, takes first 32 --
  if (wave == 0) {
    const unsigned long long* flat = &wtop[0][0];
    unsigned long long a = flat[lane];        // position = lane
    unsigned long long c = flat[lane + 64];   // position = lane + 64
#pragma unroll
    for (int k2 = 2; k2 <= 128; k2 <<= 1) {
#pragma unroll
      for (int j2 = k2 >> 1; j2 >= 1; j2 >>= 1) {
        if (j2 == 64) {  // within-lane slot exchange (only at k2 == 128)
          const unsigned long long mn = a < c ? a : c;
          const unsigned long long mx = a < c ? c : a;
          a = mn; c = mx;
        } else {
          const bool upa = ((lane & k2) == 0);
          const bool upc = (((lane + 64) & k2) == 0);
          const unsigned long long oa = __shfl_xor(a, j2);
          const unsigned long long oc = __shfl_xor(c, j2);
          const bool low = ((lane & j2) == 0);
          const unsigned long long mna = a < oa ? a : oa;
          const unsigned long long mxa = a < oa ? oa : a;
          const unsigned long long mnc = c < oc ? c : oc;
          const unsigned long long mxc = c < oc ? oc : c;
          a = (low == upa) ? mna : mxa;
          c = (low == upc) ? mnc : mxc;
        }
      }
    }
    if (lane < GSZ) knn_sh[lane] = (int)(unsigned)(a & 0xFFFFFFFFull);
  }
  __syncthreads();

  // gather + center-relative xyz; 192 output floats per group
  float* outg = grouped + ((size_t)b * NGRP + g) * GSZ * NCH;
  for (int t = tid; t < GSZ * NCH; t += 256) {
    const int n = t / 6, c2 = t % 6;
    const int idx = knn_sh[n];
    float v = P[idx * 6 + c2];
    if (c2 < 3) v = v - cen[c2];  // exact ref subtract
    outg[t] = v;
  }
}

extern "C" void kernel_launch(void* const* d_in, const int* in_sizes, int n_in,
                              void* d_out, int out_size, void* d_ws, size_t ws_size,
                              hipStream_t stream) {
  const float* points = (const float*)d_in[0];
  float* out = (float*)d_out;
  float* grouped = out;                                        // [16,512,32,6]
  float* centers = out + (size_t)BATCH * NGRP * GSZ * NCH;     // [16,512,3]

  fps_kernel<<<BATCH, FPS_T, 0, stream>>>(points, centers);
  knn_kernel<<<dim3(NGRP, BATCH), 256, 0, stream>>>(points, centers, grouped);
}

// Round 15
// 733.128 us; speedup vs baseline: 2.5714x; 1.0118x over previous
//
#include <hip/hip_runtime.h>
#include <hip/hip_bf16.h>
#include <stdint.h>

// Problem constants (fixed by reference)
#define BATCH 16
#define NPTS  8192
#define NCH   6
#define NGRP  512   // NUM_GROUPS (FPS samples)
#define GSZ   32    // GROUP_SIZE (kNN)

#define TPB    1024            // threads per block (both roles)
#define FPS_PPT 8              // fps: contiguous mapping, idx = tid*8 + j
#define FPS_W   16
#define GPB     4              // knn groups per block (4 x 256-thread subunits)
#define KNB     (BATCH * NGRP / GPB)  // 2048 knn blocks

typedef float v2f __attribute__((ext_vector_type(2)));

// DPP ctrl encodings (gfx9+): row_shr:N = 0x110|N, row_bcast15/31 = 0x142/0x143
template <int CTRL>
__device__ __forceinline__ float dpp_max_f32(float v) {
  // bound_ctrl=1 -> invalid source lanes read 0; reduced values are squared
  // distances >= 0, so max-with-0 is identity-safe. (validated r7-r14)
  const int t =
      __builtin_amdgcn_update_dpp(0, __float_as_int(v), CTRL, 0xf, 0xf, true);
  return fmaxf(v, __int_as_float(t));
}

template <int CTRL>
__device__ __forceinline__ unsigned dpp_min_u32(unsigned v) {
  // bound_ctrl=0 + old=0xFFFFFFFF -> invalid lanes yield the min identity.
  // (validated r10-r14)
  const int t = __builtin_amdgcn_update_dpp((int)0xFFFFFFFF, (int)v, CTRL,
                                            0xf, 0xf, false);
  const unsigned tu = (unsigned)t;
  return v < tu ? v : tu;
}

// ws layout (uints): [0] ticket counter; [32 + b*32] progress[b]
//
// ---------------------------------------------------------------------------
// Fused kernel, ticket roles (r5/r8-validated pattern, deadlock-free: fps
// tickets 0..15 are claimed by already-resident blocks which never wait; knn
// tickets spin only on fps progress; resident tickets < queued tickets, so
// resident knn blocks always hold the lowest outstanding groups).
//
// CU isolation WITHOUT a pad: the union LDS (fps 96 KiB cache) = 98.6 KiB
// per block -> exactly 1 block/CU for every block. fps CUs can never host
// knn waves (the r5 killer). knn occupancy = 16 waves/CU, equal to r14's
// VGPR-limited effective occupancy, and knn phase 1 is barrier-free.
//
// fps role = r7/r11 VERBATIM (516 us plateau, 3x reproduced) + r8-validated
// progress publish (agent RELEASE every 8 centers).
// knn role = r14 VERBATIM per 256-thread subunit (4 subunits per block,
// sub-block index offsets only; block-wide barriers are shared/conservative).
// Cross-XCD: knn reads centers with agent-scope atomic loads after an
// ACQUIRE spin (r5/r8-validated, absmax 0).
// ---------------------------------------------------------------------------
__global__ __launch_bounds__(TPB, 1) void fused_kernel(
    const float* __restrict__ points, float* __restrict__ grouped,
    float* __restrict__ centers, unsigned* __restrict__ ws) {
#pragma clang fp contract(off)
  __shared__ union {
    struct {  // fps role
      float cache[NPTS * 3];                 // xyz cache, 96 KiB
      unsigned long long wslot[2][FPS_W];    // ping-pong reduce slots
    } f;
    struct {  // knn role
      unsigned long long wtop[16][GSZ];      // per-wave top-32 candidates
      int knn_sh[GPB][GSZ];
    } k;
  } u;
  __shared__ unsigned ticket_sh;

  const int tid  = threadIdx.x;
  const int lane = tid & 63;
  const int wave = tid >> 6;

  if (tid == 0) ticket_sh = atomicAdd(ws, 1u);
  __syncthreads();
  const unsigned ticket = ticket_sh;

  if (ticket < BATCH) {
    // ================= FPS role: one block per batch (r11 verbatim) =======
    const int b = (int)ticket;
    const float* P = points + (size_t)b * NPTS * NCH;
    float* C = centers + (size_t)b * NGRP * 3;
    unsigned* prog = ws + 32 + b * 32;

    v2f px[4], py[4], pz[4], md[4];
    {
      float* fx = (float*)px; float* fy = (float*)py; float* fz = (float*)pz;
#pragma unroll
      for (int j = 0; j < FPS_PPT; ++j) {
        const int i = tid * FPS_PPT + j;   // contiguous mapping
        const float x = P[i * 6 + 0];
        const float y = P[i * 6 + 1];
        const float z = P[i * 6 + 2];
        fx[j] = x; fy[j] = y; fz[j] = z;
        u.f.cache[i * 3 + 0] = x;
        u.f.cache[i * 3 + 1] = y;
        u.f.cache[i * 3 + 2] = z;
      }
#pragma unroll
      for (int j = 0; j < 4; ++j)
        md[j] = (v2f){__builtin_inff(), __builtin_inff()};
    }
    __syncthreads();  // cache ready

    float lx = u.f.cache[0], ly = u.f.cache[1], lz = u.f.cache[2];

    for (int k = 1; k < NGRP; ++k) {
      if (tid == 0) {  // store center k-1; publish progress every 8
        C[(k - 1) * 3 + 0] = lx;
        C[(k - 1) * 3 + 1] = ly;
        C[(k - 1) * 3 + 2] = lz;
        if ((k & 7) == 0)
          __hip_atomic_store(prog, (unsigned)k, __ATOMIC_RELEASE,
                             __HIP_MEMORY_SCOPE_AGENT);
      }

      // ---- inner: packed min-dist update + per-thread max ----
      const v2f vlx = {lx, lx}, vly = {ly, ly}, vlz = {lz, lz};
      v2f b2 = {-__builtin_inff(), -__builtin_inff()};
#pragma unroll
      for (int j = 0; j < 4; ++j) {
        const v2f dx = px[j] - vlx;
        const v2f dy = py[j] - vly;
        const v2f dz = pz[j] - vlz;
        const v2f d  = (dx * dx + dy * dy) + dz * dz;  // ref op order, no fma
        md[j] = __builtin_elementwise_min(md[j], d);
        b2 = __builtin_elementwise_max(b2, md[j]);
      }
      const float bestv = fmaxf(b2.x, b2.y);

      // first (min) index attaining bestv: descending scan ends at min j
      unsigned idxbest = 0;
#pragma unroll
      for (int j = 3; j >= 0; --j) {
        idxbest = (md[j].y == bestv) ? (unsigned)(tid * 8 + 2 * j + 1) : idxbest;
        idxbest = (md[j].x == bestv) ? (unsigned)(tid * 8 + 2 * j)     : idxbest;
      }

      // ---- level-1: wave max via DPP (VALU only) ----
      float wv = bestv;
      wv = dpp_max_f32<0x111>(wv); wv = dpp_max_f32<0x112>(wv);
      wv = dpp_max_f32<0x114>(wv); wv = dpp_max_f32<0x118>(wv);
      wv = dpp_max_f32<0x142>(wv); wv = dpp_max_f32<0x143>(wv);
      const float wvmax =
          __int_as_float(__builtin_amdgcn_readlane(__float_as_int(wv), 63));
      const int owner = (int)__builtin_ctzll(__ballot(bestv == wvmax));
      if (lane == owner)
        u.f.wslot[k & 1][wave] =
            ((unsigned long long)__float_as_uint(wvmax) << 32) | idxbest;
      __syncthreads();  // the only barrier per step

      // ---- level-2: 16 slots + speculative coord gathers + readlanes ----
      const unsigned long long slot = u.f.wslot[k & 1][lane & 15];
      const unsigned sidx = (unsigned)(slot & 0xFFFFFFFFull);
      const float    sval = __uint_as_float((unsigned)(slot >> 32));
      const float ccx = u.f.cache[sidx * 3 + 0];
      const float ccy = u.f.cache[sidx * 3 + 1];
      const float ccz = u.f.cache[sidx * 3 + 2];

      float r = sval;
      r = dpp_max_f32<0x111>(r); r = dpp_max_f32<0x112>(r);
      r = dpp_max_f32<0x114>(r); r = dpp_max_f32<0x118>(r);
      const float gmax =
          __int_as_float(__builtin_amdgcn_readlane(__float_as_int(r), 15));
      const int sstar =
          (int)__builtin_ctzll(__ballot(sval == gmax) & 0xFFFFull);
      lx = __int_as_float(__builtin_amdgcn_readlane(__float_as_int(ccx), sstar));
      ly = __int_as_float(__builtin_amdgcn_readlane(__float_as_int(ccy), sstar));
      lz = __int_as_float(__builtin_amdgcn_readlane(__float_as_int(ccz), sstar));
    }
    if (tid == 0) {  // final center + full publish
      C[(NGRP - 1) * 3 + 0] = lx;
      C[(NGRP - 1) * 3 + 1] = ly;
      C[(NGRP - 1) * 3 + 2] = lz;
      __hip_atomic_store(prog, (unsigned)NGRP, __ATOMIC_RELEASE,
                         __HIP_MEMORY_SCOPE_AGENT);
    }
  } else {
    // ====== kNN role: 4 groups per block (4 x 256-thread subunits) ========
    const unsigned gid = ticket - BATCH;           // g-major ordering
    const int b  = (int)(gid & 15);
    const int g0 = (int)(gid >> 4) * GPB;
    const int sub  = tid >> 8;                     // subunit 0..3
    const int t256 = tid & 255;                    // tid within subunit
    const int g = g0 + sub;
    const float* P = points + (size_t)b * NPTS * NCH;
    const float* cen = centers + ((size_t)b * NGRP + g) * 3;
    unsigned* prog = ws + 32 + b * 32;

    if (tid == 0) {  // spin until all 4 centers are published
      while (__hip_atomic_load(prog, __ATOMIC_ACQUIRE,
                               __HIP_MEMORY_SCOPE_AGENT) <
             (unsigned)(g0 + GPB))
        __builtin_amdgcn_s_sleep(16);
    }
    __syncthreads();

    // center via agent-scope atomic loads (fresh across XCDs; r5/r8)
    const float cx = __hip_atomic_load(&cen[0], __ATOMIC_RELAXED,
                                       __HIP_MEMORY_SCOPE_AGENT);
    const float cy = __hip_atomic_load(&cen[1], __ATOMIC_RELAXED,
                                       __HIP_MEMORY_SCOPE_AGENT);
    const float cz = __hip_atomic_load(&cen[2], __ATOMIC_RELAXED,
                                       __HIP_MEMORY_SCOPE_AGENT);
    const float cc = (cx * cx + cy * cy) + cz * cz;

    unsigned long long keys[32];
#pragma unroll
    for (int j = 0; j < 32; ++j) {
      const int i = j * 256 + t256;
      const float2 xy = *reinterpret_cast<const float2*>(P + (size_t)i * 6);
      const float x = xy.x, y = xy.y;
      const float z = P[i * 6 + 2];
      const float xx  = (x * x + y * y) + z * z;
      const float dot = fmaf(cz, z, fmaf(cy, y, cx * x));  // einsum fma chain
      const float d2  = (cc - 2.0f * dot) + xx;
      unsigned uu = __float_as_uint(d2);
      uu = (uu & 0x80000000u) ? ~uu : (uu | 0x80000000u);  // sortable map
      keys[j] = ((unsigned long long)uu << 32) | (unsigned long long)(unsigned)i;
    }

    // 4 group mins (8 keys each) + overall min (r14 verbatim)
    unsigned long long gm[4];
#pragma unroll
    for (int g2 = 0; g2 < 4; ++g2) {
      unsigned long long m = keys[g2 * 8];
#pragma unroll
      for (int t = 1; t < 8; ++t) {
        const unsigned long long o = keys[g2 * 8 + t];
        m = m < o ? m : o;
      }
      gm[g2] = m;
    }
    unsigned long long lmin;
    {
      const unsigned long long a2 = gm[0] < gm[1] ? gm[0] : gm[1];
      const unsigned long long b3 = gm[2] < gm[3] ? gm[2] : gm[3];
      lmin = a2 < b3 ? a2 : b3;
    }

    // ---- phase 1: per-wave top-32, NO barriers (r14 verbatim) ----
    for (int r2 = 0; r2 < GSZ; ++r2) {
      const unsigned vcur = (unsigned)(lmin >> 32);
      const unsigned icur = (unsigned)(lmin & 0xFFFFFFFFull);
      unsigned vm = vcur;
      vm = dpp_min_u32<0x111>(vm); vm = dpp_min_u32<0x112>(vm);
      vm = dpp_min_u32<0x114>(vm); vm = dpp_min_u32<0x118>(vm);
      vm = dpp_min_u32<0x142>(vm); vm = dpp_min_u32<0x143>(vm);
      const unsigned vmin = (unsigned)__builtin_amdgcn_readlane((int)vm, 63);
      unsigned ic = (vcur == vmin) ? icur : 0xFFFFFFFFu;
      ic = dpp_min_u32<0x111>(ic); ic = dpp_min_u32<0x112>(ic);
      ic = dpp_min_u32<0x114>(ic); ic = dpp_min_u32<0x118>(ic);
      ic = dpp_min_u32<0x142>(ic); ic = dpp_min_u32<0x143>(ic);
      const unsigned imin = (unsigned)__builtin_amdgcn_readlane((int)ic, 63);
      const unsigned long long wk =
          ((unsigned long long)vmin << 32) | (unsigned long long)imin;

      if (lane == (int)(imin & 63u)) {  // owner removes winner
#pragma unroll
        for (int g2 = 0; g2 < 4; ++g2) {
          if (gm[g2] == wk) {
            unsigned long long m = ~0ull;
#pragma unroll
            for (int t = 0; t < 8; ++t) {
              const int s = g2 * 8 + t;
              if (keys[s] == wk) keys[s] = ~0ull;
              const unsigned long long o = keys[s];
              m = m < o ? m : o;
            }
            gm[g2] = m;
          }
        }
        const unsigned long long a2 = gm[0] < gm[1] ? gm[0] : gm[1];
        const unsigned long long b3 = gm[2] < gm[3] ? gm[2] : gm[3];
        lmin = a2 < b3 ? a2 : b3;
      }
      if (lane == 0) u.k.wtop[wave][r2] = wk;
    }
    __syncthreads();  // wtop ready

    // ---- phase 2: wave 4*sub bitonic-sorts its 128 candidates ----
    if ((wave & 3) == 0) {
      const unsigned long long* flat = &u.k.wtop[4 * sub][0];
      unsigned long long a = flat[lane];
      unsigned long long c = flat[lane + 64];
#pragma unroll
      for (int k2 = 2; k2 <= 128; k2 <<= 1) {
#pragma unroll
        for (int j2 = k2 >> 1; j2 >= 1; j2 >>= 1) {
          if (j2 == 64) {  // within-lane slot exchange (only at k2 == 128)
            const unsigned long long mn = a < c ? a : c;
            const unsigned long long mx = a < c ? c : a;
            a = mn; c = mx;
          } else {
            const bool upa = ((lane & k2) == 0);
            const bool upc = (((lane + 64) & k2) == 0);
            const unsigned long long oa = __shfl_xor(a, j2);
            const unsigned long long oc = __shfl_xor(c, j2);
            const bool low = ((lane & j2) == 0);
            const unsigned long long mna = a < oa ? a : oa;
            const unsigned long long mxa = a < oa ? oa : a;
            const unsigned long long mnc = c < oc ? c : oc;
            const unsigned long long mxc = c < oc ? oc : c;
            a = (low == upa) ? mna : mxa;
            c = (low == upc) ? mnc : mxc;
          }
        }
      }
      if (lane < GSZ) u.k.knn_sh[sub][lane] = (int)(unsigned)(a & 0xFFFFFFFFull);
    }
    __syncthreads();

    // gather + center-relative xyz; 192 output floats per group
    float* outg = grouped + ((size_t)b * NGRP + g) * GSZ * NCH;
    if (t256 < GSZ * NCH) {
      const int n = t256 / 6, c2 = t256 % 6;
      const int idx = u.k.knn_sh[sub][n];
      float v = P[idx * 6 + c2];
      if (c2 < 3) {
        const float cv = (c2 == 0) ? cx : (c2 == 1) ? cy : cz;
        v = v - cv;  // exact ref subtract
      }
      outg[t256] = v;
    }
  }
}

extern "C" void kernel_launch(void* const* d_in, const int* in_sizes, int n_in,
                              void* d_out, int out_size, void* d_ws, size_t ws_size,
                              hipStream_t stream) {
  const float* points = (const float*)d_in[0];
  float* out = (float*)d_out;
  float* grouped = out;                                        // [16,512,32,6]
  float* centers = out + (size_t)BATCH * NGRP * GSZ * NCH;     // [16,512,3]
  unsigned* ws = (unsigned*)d_ws;

  // zero ticket counter + progress flags (ws is poisoned 0xAA pre-launch)
  hipMemsetAsync(ws, 0, 4096, stream);
  fused_kernel<<<BATCH + KNB, TPB, 0, stream>>>(points, grouped, centers, ws);
}

// Round 16
// 728.126 us; speedup vs baseline: 2.5890x; 1.0069x over previous
//
#include <hip/hip_runtime.h>
#include <hip/hip_bf16.h>
#include <stdint.h>

// Problem constants (fixed by reference)
#define BATCH 16
#define NPTS  8192
#define NCH   6
#define NGRP  512   // NUM_GROUPS (FPS samples)
#define GSZ   32    // GROUP_SIZE (kNN)

#define TPB    1024            // threads per block (both roles)
#define FPS_PPT 8              // fps: contiguous mapping, idx = tid*8 + j
#define FPS_W   16
#define GPB     4              // knn groups per block (4 x 256-thread subunits)
#define KNB     (BATCH * NGRP / GPB)  // 2048 knn blocks

typedef float v2f __attribute__((ext_vector_type(2)));

// DPP ctrl encodings (gfx9+): row_shr:N = 0x110|N, row_bcast15/31 = 0x142/0x143
template <int CTRL>
__device__ __forceinline__ float dpp_max_f32(float v) {
  // bound_ctrl=1 -> invalid source lanes read 0; reduced values are squared
  // distances >= 0, so max-with-0 is identity-safe. (validated r7-r15)
  const int t =
      __builtin_amdgcn_update_dpp(0, __float_as_int(v), CTRL, 0xf, 0xf, true);
  return fmaxf(v, __int_as_float(t));
}

template <int CTRL>
__device__ __forceinline__ unsigned dpp_min_u32(unsigned v) {
  // bound_ctrl=0 + old=0xFFFFFFFF -> invalid lanes yield the min identity.
  // (validated r10-r15)
  const int t = __builtin_amdgcn_update_dpp((int)0xFFFFFFFF, (int)v, CTRL,
                                            0xf, 0xf, false);
  const unsigned tu = (unsigned)t;
  return v < tu ? v : tu;
}

// ws layout (uints): [0] ticket counter; [32 + b*32] progress[b]
//
// ---------------------------------------------------------------------------
// Fused kernel, ticket roles (r5/r8/r15-validated, deadlock-free).
// ROUND-16 CHANGE: the fps role uses the r13-validated LDS sequence-tag
// handshake instead of per-step __syncthreads. Rationale: __syncthreads
// emits `s_waitcnt vmcnt(0)` which drains wave 0's fresh C-store every step;
// under fusion the knn traffic (~27 GB/s + agent-scope poll storms) inflates
// store-ack latency, exposing ~400-700 cyc/step at the barrier (the r15
// stretch 516 -> ~700 us). The tag handshake has NO vmcnt wait; the every-8
// progress publish is moved BEFORE the C[k-1] store and publishes k-1, so
// its release-drain only covers stores >= 1 step old (already retired).
// knn role: r15 verbatim except spin sleep 16 -> 64 (cut poll traffic 4x).
//
// CU isolation: union LDS = ~96.6 KiB -> 1 block/CU for every block; fps CUs
// never host knn waves. Tag-handshake safety (r13-validated): tags strictly
// increase (no ABA), slots double-buffered by k&1, every wave writes before
// polling, all 16 waves co-resident on one CU.
// ---------------------------------------------------------------------------
__global__ __launch_bounds__(TPB, 1) void fused_kernel(
    const float* __restrict__ points, float* __restrict__ grouped,
    float* __restrict__ centers, unsigned* __restrict__ ws) {
#pragma clang fp contract(off)
  __shared__ union {
    struct {  // fps role
      float cache[NPTS * 3];                 // xyz cache, 96 KiB
      unsigned long long wdata[2][FPS_W];    // slot data (val,idx)
      unsigned wtag[2][FPS_W];               // slot sequence tags
    } f;
    struct {  // knn role
      unsigned long long wtop[16][GSZ];      // per-wave top-32 candidates
      int knn_sh[GPB][GSZ];
    } k;
  } u;
  __shared__ unsigned ticket_sh;

  const int tid  = threadIdx.x;
  const int lane = tid & 63;
  const int wave = tid >> 6;

  if (tid == 0) ticket_sh = atomicAdd(ws, 1u);
  __syncthreads();
  const unsigned ticket = ticket_sh;

  if (ticket < BATCH) {
    // ========== FPS role: one block per batch (r13 handshake) ==========
    const int b = (int)ticket;
    const float* P = points + (size_t)b * NPTS * NCH;
    float* C = centers + (size_t)b * NGRP * 3;
    unsigned* prog = ws + 32 + b * 32;

    v2f px[4], py[4], pz[4], md[4];
    {
      float* fx = (float*)px; float* fy = (float*)py; float* fz = (float*)pz;
#pragma unroll
      for (int j = 0; j < FPS_PPT; ++j) {
        const int i = tid * FPS_PPT + j;   // contiguous mapping
        const float x = P[i * 6 + 0];
        const float y = P[i * 6 + 1];
        const float z = P[i * 6 + 2];
        fx[j] = x; fy[j] = y; fz[j] = z;
        u.f.cache[i * 3 + 0] = x;
        u.f.cache[i * 3 + 1] = y;
        u.f.cache[i * 3 + 2] = z;
      }
#pragma unroll
      for (int j = 0; j < 4; ++j)
        md[j] = (v2f){__builtin_inff(), __builtin_inff()};
    }
    if (tid < 32) u.f.wtag[tid >> 4][tid & 15] = 0;  // tags below any k
    __syncthreads();  // cache + tag init ready (the ONLY barrier)

    float lx = u.f.cache[0], ly = u.f.cache[1], lz = u.f.cache[2];

    for (int k = 1; k < NGRP; ++k) {
      if (tid == 0) {
        // publish BEFORE the fresh store: release-drain covers only stores
        // >= 1 step old (retired) -> wave 0 never stalls on a fresh store.
        if ((k & 7) == 0)
          __hip_atomic_store(prog, (unsigned)(k - 1), __ATOMIC_RELEASE,
                             __HIP_MEMORY_SCOPE_AGENT);
        // fire-and-forget global store (nothing in-loop waits on it)
        C[(k - 1) * 3 + 0] = lx;
        C[(k - 1) * 3 + 1] = ly;
        C[(k - 1) * 3 + 2] = lz;
      }

      // ---- inner: packed min-dist update + per-thread max ----
      const v2f vlx = {lx, lx}, vly = {ly, ly}, vlz = {lz, lz};
      v2f b2 = {-__builtin_inff(), -__builtin_inff()};
#pragma unroll
      for (int j = 0; j < 4; ++j) {
        const v2f dx = px[j] - vlx;
        const v2f dy = py[j] - vly;
        const v2f dz = pz[j] - vlz;
        const v2f d  = (dx * dx + dy * dy) + dz * dz;  // ref op order, no fma
        md[j] = __builtin_elementwise_min(md[j], d);
        b2 = __builtin_elementwise_max(b2, md[j]);
      }
      const float bestv = fmaxf(b2.x, b2.y);

      // first (min) index attaining bestv: descending scan ends at min j
      unsigned idxbest = 0;
#pragma unroll
      for (int j = 3; j >= 0; --j) {
        idxbest = (md[j].y == bestv) ? (unsigned)(tid * 8 + 2 * j + 1) : idxbest;
        idxbest = (md[j].x == bestv) ? (unsigned)(tid * 8 + 2 * j)     : idxbest;
      }

      // ---- level-1: wave max via DPP (VALU only) ----
      float wv = bestv;
      wv = dpp_max_f32<0x111>(wv); wv = dpp_max_f32<0x112>(wv);
      wv = dpp_max_f32<0x114>(wv); wv = dpp_max_f32<0x118>(wv);
      wv = dpp_max_f32<0x142>(wv); wv = dpp_max_f32<0x143>(wv);
      const float wvmax =
          __int_as_float(__builtin_amdgcn_readlane(__float_as_int(wv), 63));
      const int owner = (int)__builtin_ctzll(__ballot(bestv == wvmax));

      const int p = k & 1;
      if (lane == owner) {
        __hip_atomic_store(&u.f.wdata[p][wave],
                           ((unsigned long long)__float_as_uint(wvmax) << 32) |
                               idxbest,
                           __ATOMIC_RELAXED, __HIP_MEMORY_SCOPE_WORKGROUP);
        __hip_atomic_store(&u.f.wtag[p][wave], (unsigned)k, __ATOMIC_RELEASE,
                           __HIP_MEMORY_SCOPE_WORKGROUP);
      }

      // ---- tag poll replaces __syncthreads (no vmcnt drain) ----
      unsigned tg;
      do {
        tg = __hip_atomic_load(&u.f.wtag[p][lane & 15], __ATOMIC_ACQUIRE,
                               __HIP_MEMORY_SCOPE_WORKGROUP);
      } while (__ballot(tg == (unsigned)k) != ~0ull);

      // ---- level-2: 16 slots + speculative coord gathers + readlanes ----
      const unsigned long long slot =
          __hip_atomic_load(&u.f.wdata[p][lane & 15], __ATOMIC_RELAXED,
                            __HIP_MEMORY_SCOPE_WORKGROUP);
      const unsigned sidx = (unsigned)(slot & 0xFFFFFFFFull);
      const float    sval = __uint_as_float((unsigned)(slot >> 32));
      const float ccx = u.f.cache[sidx * 3 + 0];
      const float ccy = u.f.cache[sidx * 3 + 1];
      const float ccz = u.f.cache[sidx * 3 + 2];

      float r = sval;
      r = dpp_max_f32<0x111>(r); r = dpp_max_f32<0x112>(r);
      r = dpp_max_f32<0x114>(r); r = dpp_max_f32<0x118>(r);
      const float gmax =
          __int_as_float(__builtin_amdgcn_readlane(__float_as_int(r), 15));
      const int sstar =
          (int)__builtin_ctzll(__ballot(sval == gmax) & 0xFFFFull);
      lx = __int_as_float(__builtin_amdgcn_readlane(__float_as_int(ccx), sstar));
      ly = __int_as_float(__builtin_amdgcn_readlane(__float_as_int(ccy), sstar));
      lz = __int_as_float(__builtin_amdgcn_readlane(__float_as_int(ccz), sstar));
    }
    if (tid == 0) {  // final center + full publish (release drains all C)
      C[(NGRP - 1) * 3 + 0] = lx;
      C[(NGRP - 1) * 3 + 1] = ly;
      C[(NGRP - 1) * 3 + 2] = lz;
      __hip_atomic_store(prog, (unsigned)NGRP, __ATOMIC_RELEASE,
                         __HIP_MEMORY_SCOPE_AGENT);
    }
  } else {
    // ====== kNN role: 4 groups per block (r15 verbatim, sleep 64) ========
    const unsigned gid = ticket - BATCH;           // g-major ordering
    const int b  = (int)(gid & 15);
    const int g0 = (int)(gid >> 4) * GPB;
    const int sub  = tid >> 8;                     // subunit 0..3
    const int t256 = tid & 255;                    // tid within subunit
    const int g = g0 + sub;
    const float* P = points + (size_t)b * NPTS * NCH;
    const float* cen = centers + ((size_t)b * NGRP + g) * 3;
    unsigned* prog = ws + 32 + b * 32;

    if (tid == 0) {  // spin until all 4 centers are published
      while (__hip_atomic_load(prog, __ATOMIC_ACQUIRE,
                               __HIP_MEMORY_SCOPE_AGENT) <
             (unsigned)(g0 + GPB))
        __builtin_amdgcn_s_sleep(64);
    }
    __syncthreads();

    // center via agent-scope atomic loads (fresh across XCDs; r5/r8/r15)
    const float cx = __hip_atomic_load(&cen[0], __ATOMIC_RELAXED,
                                       __HIP_MEMORY_SCOPE_AGENT);
    const float cy = __hip_atomic_load(&cen[1], __ATOMIC_RELAXED,
                                       __HIP_MEMORY_SCOPE_AGENT);
    const float cz = __hip_atomic_load(&cen[2], __ATOMIC_RELAXED,
                                       __HIP_MEMORY_SCOPE_AGENT);
    const float cc = (cx * cx + cy * cy) + cz * cz;

    unsigned long long keys[32];
#pragma unroll
    for (int j = 0; j < 32; ++j) {
      const int i = j * 256 + t256;
      const float2 xy = *reinterpret_cast<const float2*>(P + (size_t)i * 6);
      const float x = xy.x, y = xy.y;
      const float z = P[i * 6 + 2];
      const float xx  = (x * x + y * y) + z * z;
      const float dot = fmaf(cz, z, fmaf(cy, y, cx * x));  // einsum fma chain
      const float d2  = (cc - 2.0f * dot) + xx;
      unsigned uu = __float_as_uint(d2);
      uu = (uu & 0x80000000u) ? ~uu : (uu | 0x80000000u);  // sortable map
      keys[j] = ((unsigned long long)uu << 32) | (unsigned long long)(unsigned)i;
    }

    // 4 group mins (8 keys each) + overall min (r14 verbatim)
    unsigned long long gm[4];
#pragma unroll
    for (int g2 = 0; g2 < 4; ++g2) {
      unsigned long long m = keys[g2 * 8];
#pragma unroll
      for (int t = 1; t < 8; ++t) {
        const unsigned long long o = keys[g2 * 8 + t];
        m = m < o ? m : o;
      }
      gm[g2] = m;
    }
    unsigned long long lmin;
    {
      const unsigned long long a2 = gm[0] < gm[1] ? gm[0] : gm[1];
      const unsigned long long b3 = gm[2] < gm[3] ? gm[2] : gm[3];
      lmin = a2 < b3 ? a2 : b3;
    }

    // ---- phase 1: per-wave top-32, NO barriers (r14 verbatim) ----
    for (int r2 = 0; r2 < GSZ; ++r2) {
      const unsigned vcur = (unsigned)(lmin >> 32);
      const unsigned icur = (unsigned)(lmin & 0xFFFFFFFFull);
      unsigned vm = vcur;
      vm = dpp_min_u32<0x111>(vm); vm = dpp_min_u32<0x112>(vm);
      vm = dpp_min_u32<0x114>(vm); vm = dpp_min_u32<0x118>(vm);
      vm = dpp_min_u32<0x142>(vm); vm = dpp_min_u32<0x143>(vm);
      const unsigned vmin = (unsigned)__builtin_amdgcn_readlane((int)vm, 63);
      unsigned ic = (vcur == vmin) ? icur : 0xFFFFFFFFu;
      ic = dpp_min_u32<0x111>(ic); ic = dpp_min_u32<0x112>(ic);
      ic = dpp_min_u32<0x114>(ic); ic = dpp_min_u32<0x118>(ic);
      ic = dpp_min_u32<0x142>(ic); ic = dpp_min_u32<0x143>(ic);
      const unsigned imin = (unsigned)__builtin_amdgcn_readlane((int)ic, 63);
      const unsigned long long wk =
          ((unsigned long long)vmin << 32) | (unsigned long long)imin;

      if (lane == (int)(imin & 63u)) {  // owner removes winner
#pragma unroll
        for (int g2 = 0; g2 < 4; ++g2) {
          if (gm[g2] == wk) {
            unsigned long long m = ~0ull;
#pragma unroll
            for (int t = 0; t < 8; ++t) {
              const int s = g2 * 8 + t;
              if (keys[s] == wk) keys[s] = ~0ull;
              const unsigned long long o = keys[s];
              m = m < o ? m : o;
            }
            gm[g2] = m;
          }
        }
        const unsigned long long a2 = gm[0] < gm[1] ? gm[0] : gm[1];
        const unsigned long long b3 = gm[2] < gm[3] ? gm[2] : gm[3];
        lmin = a2 < b3 ? a2 : b3;
      }
      if (lane == 0) u.k.wtop[wave][r2] = wk;
    }
    __syncthreads();  // wtop ready

    // ---- phase 2: wave 4*sub bitonic-sorts its 128 candidates ----
    if ((wave & 3) == 0) {
      const unsigned long long* flat = &u.k.wtop[4 * sub][0];
      unsigned long long a = flat[lane];
      unsigned long long c = flat[lane + 64];
#pragma unroll
      for (int k2 = 2; k2 <= 128; k2 <<= 1) {
#pragma unroll
        for (int j2 = k2 >> 1; j2 >= 1; j2 >>= 1) {
          if (j2 == 64) {  // within-lane slot exchange (only at k2 == 128)
            const unsigned long long mn = a < c ? a : c;
            const unsigned long long mx = a < c ? c : a;
            a = mn; c = mx;
          } else {
            const bool upa = ((lane & k2) == 0);
            const bool upc = (((lane + 64) & k2) == 0);
            const unsigned long long oa = __shfl_xor(a, j2);
            const unsigned long long oc = __shfl_xor(c, j2);
            const bool low = ((lane & j2) == 0);
            const unsigned long long mna = a < oa ? a : oa;
            const unsigned long long mxa = a < oa ? oa : a;
            const unsigned long long mnc = c < oc ? c : oc;
            const unsigned long long mxc = c < oc ? oc : c;
            a = (low == upa) ? mna : mxa;
            c = (low == upc) ? mnc : mxc;
          }
        }
      }
      if (lane < GSZ) u.k.knn_sh[sub][lane] = (int)(unsigned)(a & 0xFFFFFFFFull);
    }
    __syncthreads();

    // gather + center-relative xyz; 192 output floats per group
    float* outg = grouped + ((size_t)b * NGRP + g) * GSZ * NCH;
    if (t256 < GSZ * NCH) {
      const int n = t256 / 6, c2 = t256 % 6;
      const int idx = u.k.knn_sh[sub][n];
      float v = P[idx * 6 + c2];
      if (c2 < 3) {
        const float cv = (c2 == 0) ? cx : (c2 == 1) ? cy : cz;
        v = v - cv;  // exact ref subtract
      }
      outg[t256] = v;
    }
  }
}

extern "C" void kernel_launch(void* const* d_in, const int* in_sizes, int n_in,
                              void* d_out, int out_size, void* d_ws, size_t ws_size,
                              hipStream_t stream) {
  const float* points = (const float*)d_in[0];
  float* out = (float*)d_out;
  float* grouped = out;                                        // [16,512,32,6]
  float* centers = out + (size_t)BATCH * NGRP * GSZ * NCH;     // [16,512,3]
  unsigned* ws = (unsigned*)d_ws;

  // zero ticket counter + progress flags (ws is poisoned 0xAA pre-launch)
  hipMemsetAsync(ws, 0, 4096, stream);
  fused_kernel<<<BATCH + KNB, TPB, 0, stream>>>(points, grouped, centers, ws);
}

// Round 17
// 697.608 us; speedup vs baseline: 2.7023x; 1.0437x over previous
//
#include <hip/hip_runtime.h>
#include <hip/hip_bf16.h>
#include <stdint.h>

// Problem constants (fixed by reference)
#define BATCH 16
#define NPTS  8192
#define NCH   6
#define NGRP  512   // NUM_GROUPS (FPS samples)
#define GSZ   32    // GROUP_SIZE (kNN)

#define TPB    1024            // threads per block (both roles)
#define FPS_PPT 8              // fps: contiguous mapping, idx = tid*8 + j
#define FPS_W   16
#define GPB     4              // knn groups per block (4 x 256-thread subunits)
#define KNB     (BATCH * NGRP / GPB)  // 2048 knn blocks

typedef float v2f __attribute__((ext_vector_type(2)));

// DPP ctrl encodings (gfx9+): row_shr:N = 0x110|N, row_bcast15/31 = 0x142/0x143
template <int CTRL>
__device__ __forceinline__ float dpp_max_f32(float v) {
  // bound_ctrl=1 -> invalid source lanes read 0; reduced values are squared
  // distances >= 0, so max-with-0 is identity-safe. (validated r7-r16)
  const int t =
      __builtin_amdgcn_update_dpp(0, __float_as_int(v), CTRL, 0xf, 0xf, true);
  return fmaxf(v, __int_as_float(t));
}

template <int CTRL>
__device__ __forceinline__ unsigned dpp_min_u32(unsigned v) {
  // bound_ctrl=0 + old=0xFFFFFFFF -> invalid lanes yield the min identity.
  // (validated r10-r16)
  const int t = __builtin_amdgcn_update_dpp((int)0xFFFFFFFF, (int)v, CTRL,
                                            0xf, 0xf, false);
  const unsigned tu = (unsigned)t;
  return v < tu ? v : tu;
}

// ws layout (uints): [0] ticket counter; [32 + b*32] progress[b]
//
// ---------------------------------------------------------------------------
// Fused kernel, ticket roles (r15/r16-validated, deadlock-free; 1 block/CU
// via the ~96.6 KiB union LDS -> fps CUs never host knn waves).
//
// ROUND-17 CHANGE (knn only): tie-fast-path in the phase-1 extraction round.
// After the 6-stage val-min DPP chain, ballot(vcur==vmin): if exactly one
// lane matches, its icur IS the lexicographic (val,idx) min's index (each
// lane's lmin is already its own (val,idx) min), so one readlane finishes
// the round -- the second 6-stage idx DPP chain runs only on bit-identical
// cross-lane value ties (wave-uniform fallback, bit-exact tie-break kept).
// Halves knn round issue (~26->~14 inst) and serial chain (~130->~90 cyc);
// tests the clock-throttle theory for the fused fps stretch.
//
// fps role: r16 verbatim (r13 tag handshake, publish-before-store).
// ---------------------------------------------------------------------------
__global__ __launch_bounds__(TPB, 1) void fused_kernel(
    const float* __restrict__ points, float* __restrict__ grouped,
    float* __restrict__ centers, unsigned* __restrict__ ws) {
#pragma clang fp contract(off)
  __shared__ union {
    struct {  // fps role
      float cache[NPTS * 3];                 // xyz cache, 96 KiB
      unsigned long long wdata[2][FPS_W];    // slot data (val,idx)
      unsigned wtag[2][FPS_W];               // slot sequence tags
    } f;
    struct {  // knn role
      unsigned long long wtop[16][GSZ];      // per-wave top-32 candidates
      int knn_sh[GPB][GSZ];
    } k;
  } u;
  __shared__ unsigned ticket_sh;

  const int tid  = threadIdx.x;
  const int lane = tid & 63;
  const int wave = tid >> 6;

  if (tid == 0) ticket_sh = atomicAdd(ws, 1u);
  __syncthreads();
  const unsigned ticket = ticket_sh;

  if (ticket < BATCH) {
    // ========== FPS role: one block per batch (r16 verbatim) ==========
    const int b = (int)ticket;
    const float* P = points + (size_t)b * NPTS * NCH;
    float* C = centers + (size_t)b * NGRP * 3;
    unsigned* prog = ws + 32 + b * 32;

    v2f px[4], py[4], pz[4], md[4];
    {
      float* fx = (float*)px; float* fy = (float*)py; float* fz = (float*)pz;
#pragma unroll
      for (int j = 0; j < FPS_PPT; ++j) {
        const int i = tid * FPS_PPT + j;   // contiguous mapping
        const float x = P[i * 6 + 0];
        const float y = P[i * 6 + 1];
        const float z = P[i * 6 + 2];
        fx[j] = x; fy[j] = y; fz[j] = z;
        u.f.cache[i * 3 + 0] = x;
        u.f.cache[i * 3 + 1] = y;
        u.f.cache[i * 3 + 2] = z;
      }
#pragma unroll
      for (int j = 0; j < 4; ++j)
        md[j] = (v2f){__builtin_inff(), __builtin_inff()};
    }
    if (tid < 32) u.f.wtag[tid >> 4][tid & 15] = 0;  // tags below any k
    __syncthreads();  // cache + tag init ready (the ONLY barrier)

    float lx = u.f.cache[0], ly = u.f.cache[1], lz = u.f.cache[2];

    for (int k = 1; k < NGRP; ++k) {
      if (tid == 0) {
        // publish BEFORE the fresh store: release-drain covers only stores
        // >= 1 step old (retired) -> wave 0 never stalls on a fresh store.
        if ((k & 7) == 0)
          __hip_atomic_store(prog, (unsigned)(k - 1), __ATOMIC_RELEASE,
                             __HIP_MEMORY_SCOPE_AGENT);
        // fire-and-forget global store (nothing in-loop waits on it)
        C[(k - 1) * 3 + 0] = lx;
        C[(k - 1) * 3 + 1] = ly;
        C[(k - 1) * 3 + 2] = lz;
      }

      // ---- inner: packed min-dist update + per-thread max ----
      const v2f vlx = {lx, lx}, vly = {ly, ly}, vlz = {lz, lz};
      v2f b2 = {-__builtin_inff(), -__builtin_inff()};
#pragma unroll
      for (int j = 0; j < 4; ++j) {
        const v2f dx = px[j] - vlx;
        const v2f dy = py[j] - vly;
        const v2f dz = pz[j] - vlz;
        const v2f d  = (dx * dx + dy * dy) + dz * dz;  // ref op order, no fma
        md[j] = __builtin_elementwise_min(md[j], d);
        b2 = __builtin_elementwise_max(b2, md[j]);
      }
      const float bestv = fmaxf(b2.x, b2.y);

      // first (min) index attaining bestv: descending scan ends at min j
      unsigned idxbest = 0;
#pragma unroll
      for (int j = 3; j >= 0; --j) {
        idxbest = (md[j].y == bestv) ? (unsigned)(tid * 8 + 2 * j + 1) : idxbest;
        idxbest = (md[j].x == bestv) ? (unsigned)(tid * 8 + 2 * j)     : idxbest;
      }

      // ---- level-1: wave max via DPP (VALU only) ----
      float wv = bestv;
      wv = dpp_max_f32<0x111>(wv); wv = dpp_max_f32<0x112>(wv);
      wv = dpp_max_f32<0x114>(wv); wv = dpp_max_f32<0x118>(wv);
      wv = dpp_max_f32<0x142>(wv); wv = dpp_max_f32<0x143>(wv);
      const float wvmax =
          __int_as_float(__builtin_amdgcn_readlane(__float_as_int(wv), 63));
      const int owner = (int)__builtin_ctzll(__ballot(bestv == wvmax));

      const int p = k & 1;
      if (lane == owner) {
        __hip_atomic_store(&u.f.wdata[p][wave],
                           ((unsigned long long)__float_as_uint(wvmax) << 32) |
                               idxbest,
                           __ATOMIC_RELAXED, __HIP_MEMORY_SCOPE_WORKGROUP);
        __hip_atomic_store(&u.f.wtag[p][wave], (unsigned)k, __ATOMIC_RELEASE,
                           __HIP_MEMORY_SCOPE_WORKGROUP);
      }

      // ---- tag poll replaces __syncthreads (no vmcnt drain) ----
      unsigned tg;
      do {
        tg = __hip_atomic_load(&u.f.wtag[p][lane & 15], __ATOMIC_ACQUIRE,
                               __HIP_MEMORY_SCOPE_WORKGROUP);
      } while (__ballot(tg == (unsigned)k) != ~0ull);

      // ---- level-2: 16 slots + speculative coord gathers + readlanes ----
      const unsigned long long slot =
          __hip_atomic_load(&u.f.wdata[p][lane & 15], __ATOMIC_RELAXED,
                            __HIP_MEMORY_SCOPE_WORKGROUP);
      const unsigned sidx = (unsigned)(slot & 0xFFFFFFFFull);
      const float    sval = __uint_as_float((unsigned)(slot >> 32));
      const float ccx = u.f.cache[sidx * 3 + 0];
      const float ccy = u.f.cache[sidx * 3 + 1];
      const float ccz = u.f.cache[sidx * 3 + 2];

      float r = sval;
      r = dpp_max_f32<0x111>(r); r = dpp_max_f32<0x112>(r);
      r = dpp_max_f32<0x114>(r); r = dpp_max_f32<0x118>(r);
      const float gmax =
          __int_as_float(__builtin_amdgcn_readlane(__float_as_int(r), 15));
      const int sstar =
          (int)__builtin_ctzll(__ballot(sval == gmax) & 0xFFFFull);
      lx = __int_as_float(__builtin_amdgcn_readlane(__float_as_int(ccx), sstar));
      ly = __int_as_float(__builtin_amdgcn_readlane(__float_as_int(ccy), sstar));
      lz = __int_as_float(__builtin_amdgcn_readlane(__float_as_int(ccz), sstar));
    }
    if (tid == 0) {  // final center + full publish (release drains all C)
      C[(NGRP - 1) * 3 + 0] = lx;
      C[(NGRP - 1) * 3 + 1] = ly;
      C[(NGRP - 1) * 3 + 2] = lz;
      __hip_atomic_store(prog, (unsigned)NGRP, __ATOMIC_RELEASE,
                         __HIP_MEMORY_SCOPE_AGENT);
    }
  } else {
    // ====== kNN role: 4 groups per block (r16 + tie-fast-path) ========
    const unsigned gid = ticket - BATCH;           // g-major ordering
    const int b  = (int)(gid & 15);
    const int g0 = (int)(gid >> 4) * GPB;
    const int sub  = tid >> 8;                     // subunit 0..3
    const int t256 = tid & 255;                    // tid within subunit
    const int g = g0 + sub;
    const float* P = points + (size_t)b * NPTS * NCH;
    const float* cen = centers + ((size_t)b * NGRP + g) * 3;
    unsigned* prog = ws + 32 + b * 32;

    if (tid == 0) {  // spin until all 4 centers are published
      while (__hip_atomic_load(prog, __ATOMIC_ACQUIRE,
                               __HIP_MEMORY_SCOPE_AGENT) <
             (unsigned)(g0 + GPB))
        __builtin_amdgcn_s_sleep(64);
    }
    __syncthreads();

    // center via agent-scope atomic loads (fresh across XCDs; r5/r8/r15)
    const float cx = __hip_atomic_load(&cen[0], __ATOMIC_RELAXED,
                                       __HIP_MEMORY_SCOPE_AGENT);
    const float cy = __hip_atomic_load(&cen[1], __ATOMIC_RELAXED,
                                       __HIP_MEMORY_SCOPE_AGENT);
    const float cz = __hip_atomic_load(&cen[2], __ATOMIC_RELAXED,
                                       __HIP_MEMORY_SCOPE_AGENT);
    const float cc = (cx * cx + cy * cy) + cz * cz;

    unsigned long long keys[32];
#pragma unroll
    for (int j = 0; j < 32; ++j) {
      const int i = j * 256 + t256;
      const float2 xy = *reinterpret_cast<const float2*>(P + (size_t)i * 6);
      const float x = xy.x, y = xy.y;
      const float z = P[i * 6 + 2];
      const float xx  = (x * x + y * y) + z * z;
      const float dot = fmaf(cz, z, fmaf(cy, y, cx * x));  // einsum fma chain
      const float d2  = (cc - 2.0f * dot) + xx;
      unsigned uu = __float_as_uint(d2);
      uu = (uu & 0x80000000u) ? ~uu : (uu | 0x80000000u);  // sortable map
      keys[j] = ((unsigned long long)uu << 32) | (unsigned long long)(unsigned)i;
    }

    // 4 group mins (8 keys each) + overall min (r14 verbatim)
    unsigned long long gm[4];
#pragma unroll
    for (int g2 = 0; g2 < 4; ++g2) {
      unsigned long long m = keys[g2 * 8];
#pragma unroll
      for (int t = 1; t < 8; ++t) {
        const unsigned long long o = keys[g2 * 8 + t];
        m = m < o ? m : o;
      }
      gm[g2] = m;
    }
    unsigned long long lmin;
    {
      const unsigned long long a2 = gm[0] < gm[1] ? gm[0] : gm[1];
      const unsigned long long b3 = gm[2] < gm[3] ? gm[2] : gm[3];
      lmin = a2 < b3 ? a2 : b3;
    }

    // ---- phase 1: per-wave top-32, NO barriers; tie-fast-path rounds ----
    for (int r2 = 0; r2 < GSZ; ++r2) {
      const unsigned vcur = (unsigned)(lmin >> 32);
      const unsigned icur = (unsigned)(lmin & 0xFFFFFFFFull);
      unsigned vm = vcur;
      vm = dpp_min_u32<0x111>(vm); vm = dpp_min_u32<0x112>(vm);
      vm = dpp_min_u32<0x114>(vm); vm = dpp_min_u32<0x118>(vm);
      vm = dpp_min_u32<0x142>(vm); vm = dpp_min_u32<0x143>(vm);
      const unsigned vmin = (unsigned)__builtin_amdgcn_readlane((int)vm, 63);

      // fast path: unique lane holds vmin -> its icur is the exact
      // (val,idx)-lexicographic min index (lane's lmin is already its own
      // (val,idx) min). Fallback (bit-identical cross-lane val tie, rare):
      // full idx DPP chain, identical to r10-r16.
      const unsigned long long mask = __ballot(vcur == vmin);
      unsigned imin;
      if (__builtin_popcountll(mask) == 1) {  // wave-uniform branch
        imin = (unsigned)__builtin_amdgcn_readlane(
            (int)icur, (int)__builtin_ctzll(mask));
      } else {
        unsigned ic = (vcur == vmin) ? icur : 0xFFFFFFFFu;
        ic = dpp_min_u32<0x111>(ic); ic = dpp_min_u32<0x112>(ic);
        ic = dpp_min_u32<0x114>(ic); ic = dpp_min_u32<0x118>(ic);
        ic = dpp_min_u32<0x142>(ic); ic = dpp_min_u32<0x143>(ic);
        imin = (unsigned)__builtin_amdgcn_readlane((int)ic, 63);
      }
      const unsigned long long wk =
          ((unsigned long long)vmin << 32) | (unsigned long long)imin;

      if (lane == (int)(imin & 63u)) {  // owner removes winner
#pragma unroll
        for (int g2 = 0; g2 < 4; ++g2) {
          if (gm[g2] == wk) {
            unsigned long long m = ~0ull;
#pragma unroll
            for (int t = 0; t < 8; ++t) {
              const int s = g2 * 8 + t;
              if (keys[s] == wk) keys[s] = ~0ull;
              const unsigned long long o = keys[s];
              m = m < o ? m : o;
            }
            gm[g2] = m;
          }
        }
        const unsigned long long a2 = gm[0] < gm[1] ? gm[0] : gm[1];
        const unsigned long long b3 = gm[2] < gm[3] ? gm[2] : gm[3];
        lmin = a2 < b3 ? a2 : b3;
      }
      if (lane == 0) u.k.wtop[wave][r2] = wk;
    }
    __syncthreads();  // wtop ready

    // ---- phase 2: wave 4*sub bitonic-sorts its 128 candidates ----
    if ((wave & 3) == 0) {
      const unsigned long long* flat = &u.k.wtop[4 * sub][0];
      unsigned long long a = flat[lane];
      unsigned long long c = flat[lane + 64];
#pragma unroll
      for (int k2 = 2; k2 <= 128; k2 <<= 1) {
#pragma unroll
        for (int j2 = k2 >> 1; j2 >= 1; j2 >>= 1) {
          if (j2 == 64) {  // within-lane slot exchange (only at k2 == 128)
            const unsigned long long mn = a < c ? a : c;
            const unsigned long long mx = a < c ? c : a;
            a = mn; c = mx;
          } else {
            const bool upa = ((lane & k2) == 0);
            const bool upc = (((lane + 64) & k2) == 0);
            const unsigned long long oa = __shfl_xor(a, j2);
            const unsigned long long oc = __shfl_xor(c, j2);
            const bool low = ((lane & j2) == 0);
            const unsigned long long mna = a < oa ? a : oa;
            const unsigned long long mxa = a < oa ? oa : a;
            const unsigned long long mnc = c < oc ? c : oc;
            const unsigned long long mxc = c < oc ? oc : c;
            a = (low == upa) ? mna : mxa;
            c = (low == upc) ? mnc : mxc;
          }
        }
      }
      if (lane < GSZ) u.k.knn_sh[sub][lane] = (int)(unsigned)(a & 0xFFFFFFFFull);
    }
    __syncthreads();

    // gather + center-relative xyz; 192 output floats per group
    float* outg = grouped + ((size_t)b * NGRP + g) * GSZ * NCH;
    if (t256 < GSZ * NCH) {
      const int n = t256 / 6, c2 = t256 % 6;
      const int idx = u.k.knn_sh[sub][n];
      float v = P[idx * 6 + c2];
      if (c2 < 3) {
        const float cv = (c2 == 0) ? cx : (c2 == 1) ? cy : cz;
        v = v - cv;  // exact ref subtract
      }
      outg[t256] = v;
    }
  }
}

extern "C" void kernel_launch(void* const* d_in, const int* in_sizes, int n_in,
                              void* d_out, int out_size, void* d_ws, size_t ws_size,
                              hipStream_t stream) {
  const float* points = (const float*)d_in[0];
  float* out = (float*)d_out;
  float* grouped = out;                                        // [16,512,32,6]
  float* centers = out + (size_t)BATCH * NGRP * GSZ * NCH;     // [16,512,3]
  unsigned* ws = (unsigned*)d_ws;

  // zero ticket counter + progress flags (ws is poisoned 0xAA pre-launch)
  hipMemsetAsync(ws, 0, 4096, stream);
  fused_kernel<<<BATCH + KNB, TPB, 0, stream>>>(points, grouped, centers, ws);
}